// Round 1
// baseline (791.206 us; speedup 1.0000x reference)
//
#include <hip/hip_runtime.h>

#define NN 8192
#define KSP 64
#define HS 4096
#define HMASK 4095u
#define EMPTYK 0xFFFFFFFFu
#define LOGMAX 2304

// output offsets (float32 elements): pos[64], s[8192], W[8192*8192], energy[64], age[64]
#define O_POS 0ull
#define O_S   64ull
#define O_W   8256ull
#define O_E   67117120ull
#define O_AGE 67117184ull

#define WAVE_FENCE() __asm__ volatile("s_waitcnt lgkmcnt(0)" ::: "memory")

__device__ __forceinline__ bool beforeF(float v1, int c1, float v2, int c2) {
  // strict total order: larger value first; ties -> lower index (matches jax argmax/top_k)
  return (v1 > v2) || (v1 == v2 && c1 < c2);
}

// ---------------------------------------------------------------------------
// K1: fused GEMV (z = W @ (0.95 s) + 0.05 noise -> sigmoid -> ws_s)
//     + W_out = clip(0.999*W, -2, 2) streamed while W is read.
// one wave per row; s staged (pre-scaled) in LDS.
// ---------------------------------------------------------------------------
__global__ __launch_bounds__(256) void k_gemv(const float* __restrict__ W,
    const float* __restrict__ s_in, const float* __restrict__ noise,
    float* __restrict__ Wout, float* __restrict__ s_mid)
{
  __shared__ float sv[NN];
  int tid = threadIdx.x;
  const float4* s4 = (const float4*)s_in;
  float4* sv4 = (float4*)sv;
  for (int i = tid; i < NN / 4; i += 256) {
    float4 v = s4[i];
    v.x *= 0.95f; v.y *= 0.95f; v.z *= 0.95f; v.w *= 0.95f;
    sv4[i] = v;
  }
  __syncthreads();
  int wave = tid >> 6, lane = tid & 63;
  int row = (blockIdx.x << 2) + wave;
  const float4* wr = (const float4*)(W + (size_t)row * NN);
  float4* wo = (float4*)(Wout + (size_t)row * NN);
  float acc = 0.f;
#pragma unroll
  for (int k = 0; k < 32; ++k) {
    float4 w = wr[lane + (k << 6)];
    float4 x = sv4[lane + (k << 6)];
    acc += w.x * x.x; acc += w.y * x.y; acc += w.z * x.z; acc += w.w * x.w;
    float4 o;
    o.x = fminf(fmaxf(w.x * 0.999f, -2.f), 2.f);
    o.y = fminf(fmaxf(w.y * 0.999f, -2.f), 2.f);
    o.z = fminf(fmaxf(w.z * 0.999f, -2.f), 2.f);
    o.w = fminf(fmaxf(w.w * 0.999f, -2.f), 2.f);
    wo[lane + (k << 6)] = o;
  }
#pragma unroll
  for (int off = 32; off; off >>= 1) acc += __shfl_xor(acc, off);
  if (lane == 0) {
    float z = acc + 0.05f * noise[row];
    s_mid[row] = 1.f / (1.f + expf(-z));
  }
}

// ---------------------------------------------------------------------------
// K1.5: per spark i, top-8 (relu'd, index tie-break) of base row W[pos[i]]:
// 8 rounds of argmax-with-exclusion. 64 blocks x 256 threads.
// ---------------------------------------------------------------------------
__global__ __launch_bounds__(256) void k_top8(const float* __restrict__ W,
    const int* __restrict__ pos, unsigned* __restrict__ t8c_g, float* __restrict__ t8v_g)
{
  int i = blockIdx.x;
  int row = pos[i];
  int tid = threadIdx.x, lane = tid & 63, wave = tid >> 6;
  const float4* wr4 = (const float4*)(W + (size_t)row * NN);
  float v[32];
#pragma unroll
  for (int k = 0; k < 8; ++k) {
    float4 x = wr4[tid + (k << 8)];
    v[4 * k] = x.x; v[4 * k + 1] = x.y; v[4 * k + 2] = x.z; v[4 * k + 3] = x.w;
  }
  unsigned excl = 0;
  __shared__ float rv[4]; __shared__ int rc[4]; __shared__ float rraw[4];
  __shared__ int outc[8]; __shared__ float outv[8];
  for (int m = 0; m < 8; ++m) {
    float bv = -1.f; int bc = 0x7fffffff; float braw = 0.f;
#pragma unroll
    for (int e = 0; e < 32; ++e) {
      int col = (tid << 2) + ((e >> 2) << 10) + (e & 3);
      float f = fmaxf(v[e], 0.f);
      if (!(excl & (1u << e)) && beforeF(f, col, bv, bc)) { bv = f; bc = col; braw = v[e]; }
    }
#pragma unroll
    for (int off = 32; off; off >>= 1) {
      float v2 = __shfl_xor(bv, off); int c2 = __shfl_xor(bc, off); float r2 = __shfl_xor(braw, off);
      if (beforeF(v2, c2, bv, bc)) { bv = v2; bc = c2; braw = r2; }
    }
    if (lane == 0) { rv[wave] = bv; rc[wave] = bc; rraw[wave] = braw; }
    __syncthreads();
    float gv = rv[0]; int gc = rc[0]; float graw = rraw[0];
#pragma unroll
    for (int w = 1; w < 4; ++w) {
      if (beforeF(rv[w], rc[w], gv, gc)) { gv = rv[w]; gc = rc[w]; graw = rraw[w]; }
    }
    if (tid == ((gc & 1023) >> 2)) {            // owner thread of winning col
      int e = ((gc >> 10) << 2) | (gc & 3);
      excl |= (1u << e);
    }
    if (tid == 0) { outc[m] = gc; outv[m] = graw; }
    __syncthreads();
  }
  if (tid < 8) { t8c_g[i * 8 + tid] = (unsigned)outc[tid]; t8v_g[i * 8 + tid] = outv[tid]; }
}

// ---------------------------------------------------------------------------
// K2: the serial 64-spark scan. 1 block, 1 wave (64 lanes, lockstep -> no barriers).
// All W mutations are journaled in an LDS hash (key=(row<<13)|col):
//   flag=0: value is an accumulated DELTA over base W
//   flag=1: value is ABSOLUTE (set by Hebbian, or upgraded)
// Per-row chained mod-log gives cheap "modified cells of row r" enumeration.
// argmax/top5 answered from base top8 (precomputed) + modified cells;
// exact full-row fallback if >=3 of top8 decreased or >56 row mods.
// ---------------------------------------------------------------------------
__global__ __launch_bounds__(64) void k_scan(
    const float* __restrict__ W, const float* __restrict__ s_mid,
    const float* __restrict__ energy, const int* __restrict__ pos,
    const int* __restrict__ age, const int* __restrict__ rnd,
    const int* __restrict__ stepnum,
    const unsigned* __restrict__ t8c_g, const float* __restrict__ t8v_g,
    float* __restrict__ out, unsigned* __restrict__ wsK, float* __restrict__ wsV)
{
  __shared__ float s_lds[NN];        // 32 KB  evolving s
  __shared__ unsigned hkey[HS];      // 16 KB
  __shared__ float hval[HS];         // 16 KB
  __shared__ unsigned hflag[HS / 32];//  0.5 KB
  __shared__ int head[NN];           // 32 KB  per-row chain head into log
  __shared__ unsigned eCS[LOGMAX];   //  9 KB  col | (slot<<13)
  __shared__ short eNext[LOGMAX];    //  4.5 KB
  __shared__ unsigned t8c[KSP * 8];  //  2 KB
  __shared__ float t8v[KSP * 8];     //  2 KB
  __shared__ int logCnt;
  __shared__ int f5sh[5];

  int lane = threadIdx.x;
  for (int i = lane; i < HS; i += 64) hkey[i] = EMPTYK;
  for (int i = lane; i < HS / 32; i += 64) hflag[i] = 0u;
  for (int i = lane; i < NN; i += 64) head[i] = -1;
  for (int i = lane; i < KSP * 8; i += 64) { t8c[i] = t8c_g[i]; t8v[i] = t8v_g[i]; }
  if (lane == 0) logCnt = 0;
  const float4* sm4 = (const float4*)s_mid;
  float4* sl4 = (float4*)s_lds;
  for (int i = lane; i < NN / 4; i += 64) sl4[i] = sm4[i];
  int myPos = pos[lane], myAge = age[lane], myRnd = rnd[lane];
  float myEn = energy[lane];
  int mode = stepnum[0] % 3;
  WAVE_FENCE();
  // force young sparks to 1.0 (duplicates write same value -> benign)
  if (myAge < 5 && myPos >= 0 && myPos < NN) s_lds[myPos] = 1.0f;
  WAVE_FENCE();

  int myNext = 0;
  // prefetch hebbian bases W[t8col][prev] for iteration 0
  int pf_c = 0; float pf_v = 0.f;
  {
    int pv = __shfl(myPos, 0);
    if (lane < 8) { pf_c = (int)t8c[lane]; pf_v = W[(size_t)pf_c * NN + pv]; }
  }

  for (int it = 0; it < KSP; ++it) {
    int prev = __shfl(myPos, it);
    int rn = __shfl(myRnd, it);
    float edec = __shfl(myEn, it) * 0.98f;
    float hb2 = 0.f;
    if (mode == 2) hb2 = W[(size_t)rn * NN + prev];

    // ---- candidate set: 8 base-top8 cols (overlaid) + modified cells of this row ----
    float cv = -1.f; int cc = 0x7fffffff; float pbase = 0.f; bool hasC = false;
    float tbase = 0.f; float craw = 0.f;
    if (lane < 8) {
      cc = pf_c; tbase = t8v[it * 8 + lane]; pbase = pf_v; hasC = true;
      craw = tbase;
      unsigned key = ((unsigned)prev << 13) | (unsigned)cc;
      unsigned h = (key * 2654435761u) >> 20;
      int slot = -1;
      while (true) {
        unsigned kk = hkey[h & HMASK];
        if (kk == key) { slot = (int)(h & HMASK); break; }
        if (kk == EMPTYK) break;
        h++;
      }
      if (slot >= 0) {
        float hv = hval[slot];
        craw = ((hflag[slot >> 5] >> (slot & 31)) & 1u) ? hv : tbase + hv;
      }
      cv = fmaxf(craw, 0.f);
    }
    int nDec = __popcll(__ballot(lane < 8 && craw < tbase));
    bool fallback = false;
    int cnt = 8;
    int ce = head[prev];                       // wave-uniform chain walk
    while (ce >= 0) {
      unsigned cs = eCS[ce];
      int col = (int)(cs & 8191u); int slot = (int)(cs >> 13);
      bool dup = false;
#pragma unroll
      for (int j = 0; j < 8; ++j) if ((int)t8c[it * 8 + j] == col) dup = true;
      if (!dup) {
        float hv = hval[slot];
        float raw;
        if ((hflag[slot >> 5] >> (slot & 31)) & 1u) raw = hv;
        else {
          float base = W[(size_t)prev * NN + col];   // uniform addr -> one line
          raw = base + hv;
          if (lane == 0) { hval[slot] = raw; hflag[slot >> 5] |= (1u << (slot & 31)); } // upgrade
        }
        if (cnt < 64) {
          if (lane == cnt) { cv = fmaxf(raw, 0.f); cc = col; hasC = true; pbase = W[(size_t)col * NN + prev]; }
        } else fallback = true;
        cnt++;
      }
      ce = (int)eNext[ce];
    }
    if (nDec >= 3) fallback = true;

    float t6v[6]; int t6c[6];
    if (__builtin_expect(fallback, 0)) {
      // exact top6 over full current row (base + overlay), rare path
      float s0v = -1.f, s1v = -1.f, s2v = -1.f, s3v = -1.f, s4v = -1.f, s5v = -1.f;
      int s0c = 0x7fffffff, s1c = 0x7fffffff, s2c = 0x7fffffff, s3c = 0x7fffffff, s4c = 0x7fffffff, s5c = 0x7fffffff;
      for (int t = 0; t < 128; ++t) {
        int col = lane + (t << 6);
        float raw = W[(size_t)prev * NN + col];
        unsigned key = ((unsigned)prev << 13) | (unsigned)col;
        unsigned h = (key * 2654435761u) >> 20;
        while (true) {
          unsigned kk = hkey[h & HMASK];
          if (kk == key) {
            int sl = (int)(h & HMASK); float hv = hval[sl];
            raw = ((hflag[sl >> 5] >> (sl & 31)) & 1u) ? hv : raw + hv; break;
          }
          if (kk == EMPTYK) break;
          h++;
        }
        float f = fmaxf(raw, 0.f);
        if (beforeF(f, col, s5v, s5c)) {
          s5v = f; s5c = col;
          if (beforeF(s5v, s5c, s4v, s4c)) { float tv = s4v; s4v = s5v; s5v = tv; int tc = s4c; s4c = s5c; s5c = tc; }
          if (beforeF(s4v, s4c, s3v, s3c)) { float tv = s3v; s3v = s4v; s4v = tv; int tc = s3c; s3c = s4c; s4c = tc; }
          if (beforeF(s3v, s3c, s2v, s2c)) { float tv = s2v; s2v = s3v; s3v = tv; int tc = s2c; s2c = s3c; s3c = tc; }
          if (beforeF(s2v, s2c, s1v, s1c)) { float tv = s1v; s1v = s2v; s2v = tv; int tc = s1c; s1c = s2c; s2c = tc; }
          if (beforeF(s1v, s1c, s0v, s0c)) { float tv = s0v; s0v = s1v; s1v = tv; int tc = s0c; s0c = s1c; s1c = tc; }
        }
      }
#pragma unroll
      for (int r6 = 0; r6 < 6; ++r6) {
        float bv = s0v; int bc = s0c;
#pragma unroll
        for (int off = 32; off; off >>= 1) {
          float v2 = __shfl_xor(bv, off); int c2 = __shfl_xor(bc, off);
          if (beforeF(v2, c2, bv, bc)) { bv = v2; bc = c2; }
        }
        t6v[r6] = bv; t6c[r6] = bc;
        if (s0c == bc) {
          s0v = s1v; s0c = s1c; s1v = s2v; s1c = s2c; s2v = s3v; s2c = s3c;
          s3v = s4v; s3c = s4c; s4v = s5v; s4c = s5c; s5v = -1.f; s5c = 0x7fffffff;
        }
      }
    } else {
      // bitonic sort of 64 (value,col) pairs, best-first; pads are (-1, INT_MAX)
      float sv_ = cv; int sc_ = cc;
#pragma unroll
      for (int kk2 = 2; kk2 <= 64; kk2 <<= 1) {
#pragma unroll
        for (int j = kk2 >> 1; j > 0; j >>= 1) {
          float v2 = __shfl_xor(sv_, j); int c2 = __shfl_xor(sc_, j);
          bool bef = beforeF(sv_, sc_, v2, c2);
          bool lower = (lane & j) == 0;
          bool dir = (lane & kk2) == 0;
          bool keep = ((bef == lower) == dir);
          if (!keep) { sv_ = v2; sc_ = c2; }
        }
      }
#pragma unroll
      for (int j = 0; j < 6; ++j) { t6v[j] = __shfl(sv_, j); t6c[j] = __shfl(sc_, j); }
    }

    int nxt = (mode == 2) ? rn : t6c[0];

    // ---- Hebbian base value W[nxt][prev] (prefetched for t8 candidates) ----
    float hbase;
    if (mode == 2) hbase = hb2;
    else {
      unsigned long long bm = __ballot(hasC && cc == nxt);
      if (bm) { int src = (int)__ffsll((long long)bm) - 1; hbase = __shfl(pbase, src); }
      else hbase = W[(size_t)nxt * NN + prev];
    }
    unsigned hkeyHeb = ((unsigned)nxt << 13) | (unsigned)prev;
    int hslot = -1;
    {
      unsigned h = (hkeyHeb * 2654435761u) >> 20;
      while (true) {
        unsigned kk = hkey[h & HMASK];
        if (kk == hkeyHeb) { hslot = (int)(h & HMASK); break; }
        if (kk == EMPTYK) break;
        h++;
      }
    }
    float curv = hbase;
    if (hslot >= 0) {
      float hv = hval[hslot];
      curv = ((hflag[hslot >> 5] >> (hslot & 31)) & 1u) ? hv : hbase + hv;
    }
    float newv = curv * 0.95f + s_lds[prev] * 0.05f;

    // ---- top5, fixed for the (nxt==prev) Hebbian-before-topk case ----
    int f5_0, f5_1, f5_2, f5_3, f5_4;
    if (nxt == prev) {
      float g6v[7]; int g6c[7];
      bool inT = false;
#pragma unroll
      for (int j = 0; j < 6; ++j) {
        g6v[j] = t6v[j]; g6c[j] = t6c[j];
        if (t6c[j] == prev) { g6v[j] = fmaxf(newv, 0.f); inT = true; }
      }
      g6v[6] = inT ? -1.f : fmaxf(newv, 0.f);
      g6c[6] = inT ? 0x7fffffff : prev;
#pragma unroll
      for (int a = 0; a < 6; ++a) {
#pragma unroll
        for (int b = 0; b < 6 - a; ++b) {
          if (!beforeF(g6v[b], g6c[b], g6v[b + 1], g6c[b + 1])) {
            float tv = g6v[b]; g6v[b] = g6v[b + 1]; g6v[b + 1] = tv;
            int tc = g6c[b]; g6c[b] = g6c[b + 1]; g6c[b + 1] = tc;
          }
        }
      }
      f5_0 = g6c[0]; f5_1 = g6c[1]; f5_2 = g6c[2]; f5_3 = g6c[3]; f5_4 = g6c[4];
    } else {
      f5_0 = t6c[0]; f5_1 = t6c[1]; f5_2 = t6c[2]; f5_3 = t6c[3]; f5_4 = t6c[4];
    }
    if (lane == 0) { f5sh[0] = f5_0; f5sh[1] = f5_1; f5sh[2] = f5_2; f5sh[3] = f5_3; f5sh[4] = f5_4; }
    WAVE_FENCE();

    // ---- phase a: ensure the 35 ripple cells exist in the hash (delta entries) ----
    int aslot = -1; float adelta = 0.f;
    if (lane < 35) {
      int r, c;
      if (lane < 5)       { r = prev; c = f5sh[lane]; adelta = 0.01f; }
      else if (lane < 10) { r = f5sh[lane - 5]; c = prev; adelta = 0.005f; }
      else { int q = lane - 10; r = f5sh[q / 5]; c = f5sh[q % 5]; adelta = 0.003f; }
      unsigned key = ((unsigned)r << 13) | (unsigned)c;
      unsigned h = (key * 2654435761u) >> 20;
      while (true) {
        unsigned kk = hkey[h & HMASK];
        if (kk == key) { aslot = (int)(h & HMASK); break; }
        if (kk == EMPTYK) {
          unsigned old = atomicCAS(&hkey[h & HMASK], EMPTYK, key);
          if (old == EMPTYK) {
            int s2 = (int)(h & HMASK);
            hval[s2] = 0.f; aslot = s2;
            int li = atomicAdd(&logCnt, 1);
            eCS[li] = (unsigned)c | ((unsigned)s2 << 13);
            int oh = atomicExch(&head[r], li);
            eNext[li] = (short)oh;
            break;
          }
          if (old == key) { aslot = (int)(h & HMASK); break; }
        }
        h++;
      }
    }
    WAVE_FENCE();
    // ---- Hebbian set (absolute), then s update ----
    if (lane == 0) {
      int s2 = hslot;
      if (s2 < 0) {
        unsigned h = (hkeyHeb * 2654435761u) >> 20;
        while (true) {
          unsigned kk = hkey[h & HMASK];
          if (kk == hkeyHeb) { s2 = (int)(h & HMASK); break; }
          if (kk == EMPTYK) {
            s2 = (int)(h & HMASK); hkey[s2] = hkeyHeb;
            int li = logCnt; logCnt = li + 1;
            eCS[li] = (unsigned)prev | ((unsigned)s2 << 13);
            int oh = head[nxt]; head[nxt] = li; eNext[li] = (short)oh;
            break;
          }
          h++;
        }
      }
      hval[s2] = newv;
      hflag[s2 >> 5] |= (1u << (s2 & 31));
      s_lds[nxt] = edec;
    }
    WAVE_FENCE();
    // ---- phase b: the 35 commutative adds ----
    if (lane < 35) atomicAdd(&hval[aslot], adelta);
    if (lane == it) myNext = nxt;
    // ---- prefetch hebbian bases for next iteration ----
    if (it + 1 < KSP) {
      int pv = __shfl(myPos, it + 1);
      if (lane < 8) { pf_c = (int)t8c[(it + 1) * 8 + lane]; pf_v = W[(size_t)pf_c * NN + pv]; }
    }
    WAVE_FENCE();
  }

  // ---- epilogue: s, spark outputs, resolved hash dump ----
  WAVE_FENCE();
  const float4* sl4c = (const float4*)s_lds;
  float4* outs4 = (float4*)(out + O_S);
  for (int i = lane; i < NN / 4; i += 64) outs4[i] = sl4c[i];
  {
    float ed = myEn * 0.98f;
    bool rst = ed < 0.05f;
    int pn = rst ? (lane % NN) : myNext;
    out[O_POS + lane] = (float)pn;
    out[O_E + lane] = rst ? 1.0f : ed;
    out[O_AGE + lane] = (float)(rst ? 0 : (myAge + 1));
  }
  for (int s2 = lane; s2 < HS; s2 += 64) {
    unsigned kk = hkey[s2];
    float res = 0.f;
    if (kk != EMPTYK) {
      float hv = hval[s2];
      if ((hflag[s2 >> 5] >> (s2 & 31)) & 1u) res = hv;
      else { int r = (int)(kk >> 13), c = (int)(kk & 8191u); res = W[(size_t)r * NN + c] + hv; }
    }
    wsK[s2] = kk; wsV[s2] = res;
  }
}

// ---------------------------------------------------------------------------
// K4: patch the <=2304 modified W cells into the already-written W output.
// ---------------------------------------------------------------------------
__global__ __launch_bounds__(256) void k_patch(const unsigned* __restrict__ wsK,
    const float* __restrict__ wsV, float* __restrict__ out)
{
  int t = blockIdx.x * 256 + threadIdx.x;
  if (t >= HS) return;
  unsigned kk = wsK[t];
  if (kk != EMPTYK) {
    int r = (int)(kk >> 13), c = (int)(kk & 8191u);
    out[O_W + (size_t)r * NN + c] = fminf(fmaxf(wsV[t] * 0.999f, -2.f), 2.f);
  }
}

extern "C" void kernel_launch(void* const* d_in, const int* in_sizes, int n_in,
                              void* d_out, int out_size, void* d_ws, size_t ws_size,
                              hipStream_t stream) {
  const float* W      = (const float*)d_in[0];
  const float* s      = (const float*)d_in[1];
  const float* noise  = (const float*)d_in[2];
  // d_in[3] = unif: unused (scalar gumbel per step cannot change argmax)
  const float* energy = (const float*)d_in[4];
  const int* pos      = (const int*)d_in[5];
  const int* age      = (const int*)d_in[6];
  const int* rnd      = (const int*)d_in[7];
  const int* stepn    = (const int*)d_in[8];
  float* out = (float*)d_out;
  float* ws = (float*)d_ws;
  // ws layout (floats): s_mid[8192] | hashKeys[4096] | hashVals[4096] | t8c[512] | t8v[512]
  float* ws_s = ws;
  unsigned* wsK = (unsigned*)(ws + 8192);
  float* wsV = ws + 8192 + 4096;
  unsigned* wsT8C = (unsigned*)(ws + 16384);
  float* wsT8V = ws + 16384 + 512;

  k_gemv<<<2048, 256, 0, stream>>>(W, s, noise, out + O_W, ws_s);
  k_top8<<<64, 256, 0, stream>>>(W, pos, wsT8C, wsT8V);
  k_scan<<<1, 64, 0, stream>>>(W, ws_s, energy, pos, age, rnd, stepn, wsT8C, wsT8V, out, wsK, wsV);
  k_patch<<<16, 256, 0, stream>>>(wsK, wsV, out);
}